// Round 8
// baseline (198.560 us; speedup 1.0000x reference)
//
#include <hip/hip_runtime.h>
#include <hip/hip_bf16.h>
#include <stdint.h>

// Problem constants
#define EXP 8
#define DIM 1024
#define SEQL 512
#define BATCH 8
#define OUT_FINAL_N (BATCH * SEQL * DIM)   // 4194304
#define OFF_AUX    4194304
#define OFF_MASK   4194305
#define OFF_LOGITS 4194369

typedef __bf16 bf16_t;
typedef bf16_t bf16x8 __attribute__((ext_vector_type(8)));
typedef bf16_t bf16x4 __attribute__((ext_vector_type(4)));
typedef float  f32x4  __attribute__((ext_vector_type(4)));

typedef __attribute__((address_space(1))) void* as1p;
typedef __attribute__((address_space(3))) void* as3p;

__device__ __forceinline__ void glds16(const void* g, void* l) {
  // async global->LDS, 16B per lane; LDS dest = wave-uniform base + lane*16
  __builtin_amdgcn_global_load_lds((as1p)(void*)g, (as3p)l, 16, 0, 0);
}

// ---------------------------------------------------------------------------
// prep_kernel: fused { w1 transpose-cast | x cast | router }.  (R7 verbatim;
// w2's transpose is hosted inside gemm1.)  grid.x = 2048 + 512 + 1.
// ---------------------------------------------------------------------------
__global__ __launch_bounds__(256) void prep_kernel(
    const float* __restrict__ x, const float* __restrict__ dec,
    const float* __restrict__ rw, const float* __restrict__ rb,
    const float* __restrict__ w1, const float* __restrict__ w2,
    bf16_t* __restrict__ xb, bf16_t* __restrict__ w1t, bf16_t* __restrict__ w2t,
    float* __restrict__ out_aux, float* __restrict__ out_mask,
    float* __restrict__ out_logits, int* __restrict__ idx_ws,
    float* __restrict__ w_ws) {
  __shared__ __align__(16) char tileb[9216];   // bf16 [64 n][72 k], 144B pitch
  __shared__ float part[256];
  __shared__ float lg64[64];
  __shared__ float probs[64];
  __shared__ float msk[64];
  const int bid = blockIdx.x;
  const int t = threadIdx.x;

  if (bid < 2048) {
    // ---- transpose-cast w1: matrix z, tile = 64 k-rows x 64 n-cols ----
    const int z = bid >> 8;
    const int rem = bid & 255;
    const int k0 = (rem >> 4) * 64;
    const int n0 = (rem & 15) * 64;
    const float* src = w1 + (size_t)z * DIM * DIM;
    bf16_t* dst = w1t + (size_t)z * DIM * DIM;
    const int c4 = t & 15;
    const int rr = t >> 4;
    float4 v[4];
#pragma unroll
    for (int r = 0; r < 4; ++r)
      v[r] = *(const float4*)(src + (size_t)(k0 + rr * 4 + r) * DIM + n0 + c4 * 4);
    const float* vp = (const float*)v;
#pragma unroll
    for (int c = 0; c < 4; ++c) {
      bf16x4 o;
#pragma unroll
      for (int jk = 0; jk < 4; ++jk) o[jk] = (bf16_t)vp[jk * 4 + c];
      *(bf16x4*)(tileb + (c4 * 4 + c) * 144 + rr * 8) = o;
    }
    __syncthreads();
#pragma unroll
    for (int ii = 0; ii < 2; ++ii) {
      const int n = (t >> 3) + 32 * ii;
      const int j = t & 7;
      bf16x8 vv = *(const bf16x8*)(tileb + n * 144 + j * 16);
      *(bf16x8*)(dst + (size_t)(n0 + n) * DIM + k0 + j * 8) = vv;
    }
  } else if (bid < 2048 + 512) {
    // ---- cast x ----
    const int i0 = (bid - 2048) * 2048 + t;
    float4 v[8];
#pragma unroll
    for (int i = 0; i < 8; ++i) v[i] = ((const float4*)x)[i0 + i * 256];
#pragma unroll
    for (int i = 0; i < 8; ++i) {
      bf16x4 o;
      o[0] = (bf16_t)v[i].x; o[1] = (bf16_t)v[i].y;
      o[2] = (bf16_t)v[i].z; o[3] = (bf16_t)v[i].w;
      ((bf16x4*)xb)[i0 + i * 256] = o;
    }
  } else {
    // ---- router ----
    const int p = t >> 2, seg = t & 3;
    const int b = p >> 3, e = p & 7;
    const float4* dv = (const float4*)(dec + b * DIM + seg * 256);
    const float4* wv = (const float4*)(rw + e * DIM + seg * 256);
    float s = 0.f;
#pragma unroll 8
    for (int i = 0; i < 64; ++i) {
      float4 a = dv[i], c = wv[i];
      s += a.x * c.x + a.y * c.y + a.z * c.z + a.w * c.w;
    }
    part[t] = s;
    __syncthreads();
    if (seg == 0) {
      float l = part[t] + part[t + 1] + part[t + 2] + part[t + 3] + rb[e];
      lg64[p] = l;
      out_logits[p] = l;
    }
    __syncthreads();
    if (t < 8) {
      float l[8];
      float mx = -1e30f;
#pragma unroll
      for (int k = 0; k < 8; ++k) { l[k] = lg64[t * 8 + k]; mx = fmaxf(mx, l[k]); }
      float pe[8];
      float sum = 0.f;
#pragma unroll
      for (int k = 0; k < 8; ++k) { pe[k] = expf(l[k] - mx); sum += pe[k]; }
      float inv = 1.f / sum;
#pragma unroll
      for (int k = 0; k < 8; ++k) { pe[k] *= inv; probs[t * 8 + k] = pe[k]; }
      int i0 = 0;
#pragma unroll
      for (int k = 1; k < 8; ++k) if (pe[k] > pe[i0]) i0 = k;
      int i1 = (i0 == 0) ? 1 : 0;
#pragma unroll
      for (int k = 0; k < 8; ++k) if (k != i0 && pe[k] > pe[i1]) i1 = k;
      float p0 = pe[i0], p1 = pe[i1];
      float invs = 1.f / (p0 + p1);
      idx_ws[t * 2] = i0;
      idx_ws[t * 2 + 1] = i1;
      w_ws[t * 2] = p0 * invs;
      w_ws[t * 2 + 1] = p1 * invs;
#pragma unroll
      for (int k = 0; k < 8; ++k) {
        float m = (k == i0 || k == i1) ? 1.f : 0.f;
        msk[t * 8 + k] = m;
        out_mask[t * 8 + k] = m;
      }
    }
    __syncthreads();
    if (t == 0) {
      float aux = 0.f;
#pragma unroll
      for (int k = 0; k < 8; ++k) {
        float mp = 0.f, mm = 0.f;
#pragma unroll
        for (int bb = 0; bb < 8; ++bb) { mp += probs[bb * 8 + k]; mm += msk[bb * 8 + k]; }
        aux += (mp * 0.125f) * (mm * 0.125f);
      }
      out_aux[0] = 8.f * aux;
    }
  }
}

// ---------------------------------------------------------------------------
// GEMM1 (R8): 256-thr, 128x128 tile, BK=32, **4-buffer depth-3 prefetch**.
// Single delta vs R3's measured config (3-buffer depth-2): one more buffer.
// Rationale: per-k-step compute ~54ns < L2/L3 load latency ~80-225ns, so
// depth-2 exposed part of every vmcnt wait.  Depth-3 (stages kt,kt+1,kt+2 in
// flight; steady vmcnt(8)) covers it.  LDS 4x(8K+8K)=64KB -> still 2
// independent blocks/CU (the cross-block overlap R4's lockstep lost).
// grid 1-D: 512 gemm blocks (bN 8, bM 4, slot 16) + 1024 hosted w2-transpose
// blocks (2 tiles each, R5 body) filling idle waves behind the gemm blocks.
// ---------------------------------------------------------------------------
__global__ __launch_bounds__(256, 2) void gemm1_kernel(const bf16_t* __restrict__ xb,
                                                       const bf16_t* __restrict__ w1t,
                                                       const float* __restrict__ b1,
                                                       const int* __restrict__ topk_idx,
                                                       bf16_t* __restrict__ hidden,
                                                       const float* __restrict__ w2,
                                                       bf16_t* __restrict__ w2t) {
  __shared__ __align__(16) char smem[65536];   // sA 4x8K | sB 4x8K
  const int bid = blockIdx.x;
  const int tid = threadIdx.x;

  if (bid >= 512) {
    // ---- hosted w2 transpose: 2 sequential 64k x 64n tiles ----
    char* tb = smem;
    const int base = (bid - 512) * 2;
#pragma unroll
    for (int it = 0; it < 2; ++it) {
      const int tile = base + it;                // 0..2047
      const int z = tile >> 8;                   // 8 matrices
      const int rem = tile & 255;
      const int k0 = (rem >> 4) * 64;
      const int n0 = (rem & 15) * 64;
      const float* src = w2 + (size_t)z * DIM * DIM;
      bf16_t* dst = w2t + (size_t)z * DIM * DIM;
      const int c4 = tid & 15;
      const int rr = tid >> 4;
      float4 v[4];
#pragma unroll
      for (int r = 0; r < 4; ++r)
        v[r] = *(const float4*)(src + (size_t)(k0 + rr * 4 + r) * DIM + n0 + c4 * 4);
      const float* vp = (const float*)v;
#pragma unroll
      for (int c = 0; c < 4; ++c) {
        bf16x4 o;
#pragma unroll
        for (int jk = 0; jk < 4; ++jk) o[jk] = (bf16_t)vp[jk * 4 + c];
        *(bf16x4*)(tb + (c4 * 4 + c) * 144 + rr * 8) = o;
      }
      __syncthreads();
#pragma unroll
      for (int ii = 0; ii < 2; ++ii) {
        const int n = (tid >> 3) + 32 * ii;
        const int j = tid & 7;
        bf16x8 vv = *(const bf16x8*)(tb + n * 144 + j * 16);
        *(bf16x8*)(dst + (size_t)(n0 + n) * DIM + k0 + j * 8) = vv;
      }
      __syncthreads();                           // before next tile's writes
    }
    return;
  }

  // ---- gemm: decode 1-D ----
  const int bN = bid & 7, bM = (bid >> 3) & 3, slot = bid >> 5;
  const int t = tid;
  const int b = slot >> 1;
  const int e = topk_idx[slot];

  const bf16_t* A  = xb + ((size_t)b * SEQL + bM * 128) * DIM;
  const bf16_t* Bt = w1t + ((size_t)e * DIM + bN * 128) * DIM;

  char* sA = smem;            // 4 buffers x 8192
  char* sB = smem + 32768;    // 4 buffers x 8192

  // staging addresses (XOR-swizzled global source -> linear LDS dest)
  const int rl = t >> 2, cp = (t & 3) ^ (rl & 3);   // rows 0..63
  const bf16_t* ga0 = A + (size_t)rl * DIM + cp * 8;
  const bf16_t* ga1 = ga0 + (size_t)64 * DIM;
  const bf16_t* gb0 = Bt + (size_t)rl * DIM + cp * 8;
  const bf16_t* gb1 = gb0 + (size_t)64 * DIM;

  // fragment read pointers (R3-verified geometry)
  const int lane = t & 63, w = t >> 6;
  const int wr = w >> 1, wc = w & 1;
  const int m15 = lane & 15, q = lane >> 4;
  const char* ra[4];
  const char* rb[4];
#pragma unroll
  for (int i = 0; i < 4; ++i) {
    const int r = wr * 64 + i * 16 + m15;
    ra[i] = sA + r * 64 + ((q ^ (r & 3)) * 16);
    const int n = wc * 64 + i * 16 + m15;
    rb[i] = sB + n * 64 + ((q ^ (n & 3)) * 16);
  }

  f32x4 acc[4][4];
#pragma unroll
  for (int i = 0; i < 4; ++i)
#pragma unroll
    for (int j = 0; j < 4; ++j) acc[i][j] = {0.f, 0.f, 0.f, 0.f};

  auto STAGE = [&](int kt, int nb) {
    const int off = kt * 32;
    glds16(ga0 + off, sA + nb * 8192 + t * 16);
    glds16(ga1 + off, sA + nb * 8192 + 4096 + t * 16);
    glds16(gb0 + off, sB + nb * 8192 + t * 16);
    glds16(gb1 + off, sB + nb * 8192 + 4096 + t * 16);
  };

  // prologue: stages 0,1,2 in flight (12 loads/thread)
  STAGE(0, 0);
  STAGE(1, 1);
  STAGE(2, 2);

  for (int kt = 0; kt < 32; ++kt) {
    if (kt < 30) {
      asm volatile("s_waitcnt vmcnt(8)" ::: "memory");   // stage(kt) landed
    } else if (kt == 30) {
      asm volatile("s_waitcnt vmcnt(4)" ::: "memory");
    } else {
      asm volatile("s_waitcnt vmcnt(0)" ::: "memory");
    }
    __builtin_amdgcn_s_barrier();
    asm volatile("" ::: "memory");
    if (kt < 29) {                      // stage kt+3 into buffer read at kt-1
      STAGE(kt + 3, (kt + 3) & 3);
    }
    const int cur = kt & 3;
    bf16x8 af[4], bfr[4];
#pragma unroll
    for (int i = 0; i < 4; ++i) af[i] = *(const bf16x8*)(ra[i] + cur * 8192);
#pragma unroll
    for (int j = 0; j < 4; ++j) bfr[j] = *(const bf16x8*)(rb[j] + cur * 8192);
    __builtin_amdgcn_s_setprio(1);
#pragma unroll
    for (int i = 0; i < 4; ++i)
#pragma unroll
      for (int j = 0; j < 4; ++j)
        acc[i][j] = __builtin_amdgcn_mfma_f32_16x16x32_bf16(af[i], bfr[j], acc[i][j], 0, 0, 0);
    __builtin_amdgcn_s_setprio(0);
  }

  // epilogue: bias + relu + cast, LDS bounce for 16B stores.
  // C/D layout: col = lane&15, row = quad*4 + reg (m89-verified).
  __syncthreads();
  bf16_t* hb = (bf16_t*)smem;            // [128][136] halfwords
  const float* be = b1 + e * DIM;
#pragma unroll
  for (int i = 0; i < 4; ++i)
#pragma unroll
    for (int j = 0; j < 4; ++j) {
      const int colL = wc * 64 + j * 16 + m15;
      const float bias = be[bN * 128 + colL];
#pragma unroll
      for (int r = 0; r < 4; ++r) {
        const int rowL = wr * 64 + i * 16 + q * 4 + r;
        hb[rowL * 136 + colL] = (bf16_t)fmaxf(acc[i][j][r] + bias, 0.f);
      }
    }
  __syncthreads();
  bf16_t* H = hidden + (size_t)slot * SEQL * DIM + ((size_t)bM * 128) * DIM + bN * 128;
#pragma unroll
  for (int ii = 0; ii < 8; ++ii) {
    const int r = (t >> 4) + 16 * ii;
    const int c = t & 15;
    bf16x8 vv = *(const bf16x8*)(hb + r * 136 + c * 8);
    *(bf16x8*)(H + (size_t)r * DIM + c * 8) = vv;
  }
}

// ---------------------------------------------------------------------------
// GEMM2 (R8): R4's paired-group 512-thr structure + 4-buffer depth-3 upgrade.
// Group g = slot 2b+g (own A = hidden[slot], own B = w2t[e_g]); combine via
// LDS scratch in 4 chunks.  LDS 128KB: per group sA 4x8K | sB 4x8K.
// Steady vmcnt(8); grid (8 N, 4 M, 8 b) = 256 blocks.
// ---------------------------------------------------------------------------
__global__ __launch_bounds__(512, 2) void gemm2_kernel(const bf16_t* __restrict__ hidden,
                                                       const bf16_t* __restrict__ w2t,
                                                       const float* __restrict__ b2,
                                                       const int* __restrict__ topk_idx,
                                                       const float* __restrict__ topk_w,
                                                       float* __restrict__ out) {
  __shared__ __align__(16) char smem[131072];   // per group: sA 4x8K | sB 4x8K
  const int tid = threadIdx.x;
  const int g = tid >> 8;
  const int t = tid & 255;
  const int bN = blockIdx.x, bM = blockIdx.y, b = blockIdx.z;
  const int slot = b * 2 + g;
  const int e = topk_idx[slot];
  const float sg = topk_w[slot];

  const bf16_t* A  = hidden + ((size_t)slot * SEQL + bM * 128) * DIM;
  const bf16_t* Bt = w2t + ((size_t)e * DIM + bN * 128) * DIM;

  char* sA = smem + g * 65536;
  char* sB = sA + 32768;

  const int rl = t >> 2, cp = (t & 3) ^ (rl & 3);          // rows 0..63
  const bf16_t* gA0 = A + (size_t)rl * DIM + cp * 8;
  const bf16_t* gA1 = gA0 + (size_t)64 * DIM;
  const bf16_t* gB0 = Bt + (size_t)rl * DIM + cp * 8;
  const bf16_t* gB1 = gB0 + (size_t)64 * DIM;

  const int lane = tid & 63, wg = (tid >> 6) & 3;
  const int wr = wg >> 1, wc = wg & 1;
  const int m15 = lane & 15, q = lane >> 4;
  const char* ra[4];
  const char* rb[4];
#pragma unroll
  for (int i = 0; i < 4; ++i) {
    const int r = wr * 64 + i * 16 + m15;
    ra[i] = sA + r * 64 + ((q ^ (r & 3)) * 16);
    const int n = wc * 64 + i * 16 + m15;
    rb[i] = sB + n * 64 + ((q ^ (n & 3)) * 16);
  }

  f32x4 acc[4][4];
#pragma unroll
  for (int i = 0; i < 4; ++i)
#pragma unroll
    for (int j = 0; j < 4; ++j) acc[i][j] = {0.f, 0.f, 0.f, 0.f};

  auto STAGE = [&](int kt, int nb) {
    const int off = kt * 32;
    glds16(gA0 + off, sA + nb * 8192 + t * 16);
    glds16(gA1 + off, sA + nb * 8192 + 4096 + t * 16);
    glds16(gB0 + off, sB + nb * 8192 + t * 16);
    glds16(gB1 + off, sB + nb * 8192 + 4096 + t * 16);
  };

  STAGE(0, 0);
  STAGE(1, 1);
  STAGE(2, 2);

  for (int kt = 0; kt < 32; ++kt) {
    if (kt < 30) {
      asm volatile("s_waitcnt vmcnt(8)" ::: "memory");
    } else if (kt == 30) {
      asm volatile("s_waitcnt vmcnt(4)" ::: "memory");
    } else {
      asm volatile("s_waitcnt vmcnt(0)" ::: "memory");
    }
    __builtin_amdgcn_s_barrier();
    asm volatile("" ::: "memory");
    if (kt < 29) {
      STAGE(kt + 3, (kt + 3) & 3);
    }
    const int cur = kt & 3;
    bf16x8 af[4], bfr[4];
#pragma unroll
    for (int i = 0; i < 4; ++i) af[i] = *(const bf16x8*)(ra[i] + cur * 8192);
#pragma unroll
    for (int j = 0; j < 4; ++j) bfr[j] = *(const bf16x8*)(rb[j] + cur * 8192);
    __builtin_amdgcn_s_setprio(1);
#pragma unroll
    for (int i = 0; i < 4; ++i)
#pragma unroll
      for (int j = 0; j < 4; ++j)
        acc[i][j] = __builtin_amdgcn_mfma_f32_16x16x32_bf16(af[i], bfr[j], acc[i][j], 0, 0, 0);
    __builtin_amdgcn_s_setprio(0);
  }

  // ---- combine: group1 -> LDS scratch (16KB chunks) -> group0 adds ----
  __syncthreads();               // all staging reads done; smem reusable
  float* scr = (float*)smem;     // [16][256] fp32 per chunk
  const float w0 = topk_w[b * 2], w1v = topk_w[b * 2 + 1];
  const float* be0 = b2 + topk_idx[b * 2] * DIM;
  const float* be1 = b2 + topk_idx[b * 2 + 1] * DIM;
  float* O = out + (size_t)b * SEQL * DIM;
#pragma unroll
  for (int i = 0; i < 4; ++i) {
    if (g == 1) {
#pragma unroll
      for (int j = 0; j < 4; ++j)
#pragma unroll
        for (int r = 0; r < 4; ++r)
          scr[(j * 4 + r) * 256 + t] = sg * acc[i][j][r];
    }
    __syncthreads();
    if (g == 0) {
#pragma unroll
      for (int j = 0; j < 4; ++j) {
        const int col = bN * 128 + wc * 64 + j * 16 + m15;
        const float bb = w0 * be0[col] + w1v * be1[col];
        const int row = bM * 128 + wr * 64 + i * 16 + q * 4;
#pragma unroll
        for (int r = 0; r < 4; ++r)
          O[(size_t)(row + r) * DIM + col] =
              sg * acc[i][j][r] + scr[(j * 4 + r) * 256 + t] + bb;
      }
    }
    __syncthreads();
  }
}

// ---------------------------------------------------------------------------
extern "C" void kernel_launch(void* const* d_in, const int* in_sizes, int n_in,
                              void* d_out, int out_size, void* d_ws, size_t ws_size,
                              hipStream_t stream) {
  const float* x   = (const float*)d_in[0];
  const float* dec = (const float*)d_in[1];
  const float* rw  = (const float*)d_in[2];
  const float* rb  = (const float*)d_in[3];
  const float* w1  = (const float*)d_in[4];
  const float* w2  = (const float*)d_in[5];
  const float* b1  = (const float*)d_in[6];
  const float* b2  = (const float*)d_in[7];
  float* out = (float*)d_out;

  // ws layout: xb 8MB | w1t 16MB | w2t 16MB | hidden 16MB | router scratch
  char* ws = (char*)d_ws;
  bf16_t* xb   = (bf16_t*)(ws);
  bf16_t* w1t  = (bf16_t*)(ws + (8u << 20));
  bf16_t* w2t  = (bf16_t*)(ws + (24u << 20));
  bf16_t* hid  = (bf16_t*)(ws + (40u << 20));
  int*    idxw = (int*)(ws + (56u << 20));
  float*  ww   = (float*)(ws + (56u << 20) + 64);

  hipLaunchKernelGGL(prep_kernel, dim3(2048 + 512 + 1), dim3(256), 0, stream,
                     x, dec, rw, rb, w1, w2, xb, w1t, w2t,
                     out + OFF_AUX, out + OFF_MASK, out + OFF_LOGITS, idxw, ww);
  hipLaunchKernelGGL(gemm1_kernel, dim3(512 + 1024), dim3(256), 0, stream,
                     xb, w1t, b1, idxw, hid, w2, w2t);
  hipLaunchKernelGGL(gemm2_kernel, dim3(8, 4, 8), dim3(512), 0, stream,
                     hid, w2t, b2, idxw, ww, out);
}

// Round 9
// 191.851 us; speedup vs baseline: 1.0350x; 1.0350x over previous
//
#include <hip/hip_runtime.h>
#include <hip/hip_bf16.h>
#include <stdint.h>

// Problem constants
#define EXP 8
#define DIM 1024
#define SEQL 512
#define BATCH 8
#define OUT_FINAL_N (BATCH * SEQL * DIM)   // 4194304
#define OFF_AUX    4194304
#define OFF_MASK   4194305
#define OFF_LOGITS 4194369

typedef __bf16 bf16_t;
typedef bf16_t bf16x8 __attribute__((ext_vector_type(8)));
typedef bf16_t bf16x4 __attribute__((ext_vector_type(4)));
typedef float  f32x4  __attribute__((ext_vector_type(4)));

typedef __attribute__((address_space(1))) void* as1p;
typedef __attribute__((address_space(3))) void* as3p;

__device__ __forceinline__ void glds16(const void* g, void* l) {
  // async global->LDS, 16B per lane; LDS dest = wave-uniform base + lane*16
  __builtin_amdgcn_global_load_lds((as1p)(void*)g, (as3p)l, 16, 0, 0);
}

// ---------------------------------------------------------------------------
// prep_kernel: fused { w1 transpose-cast | x cast | router }.  (R7 verbatim;
// w2's transpose is hosted inside gemm1.)  grid.x = 2048 + 512 + 1.
// ---------------------------------------------------------------------------
__global__ __launch_bounds__(256) void prep_kernel(
    const float* __restrict__ x, const float* __restrict__ dec,
    const float* __restrict__ rw, const float* __restrict__ rb,
    const float* __restrict__ w1, const float* __restrict__ w2,
    bf16_t* __restrict__ xb, bf16_t* __restrict__ w1t, bf16_t* __restrict__ w2t,
    float* __restrict__ out_aux, float* __restrict__ out_mask,
    float* __restrict__ out_logits, int* __restrict__ idx_ws,
    float* __restrict__ w_ws) {
  __shared__ __align__(16) char tileb[9216];   // bf16 [64 n][72 k], 144B pitch
  __shared__ float part[256];
  __shared__ float lg64[64];
  __shared__ float probs[64];
  __shared__ float msk[64];
  const int bid = blockIdx.x;
  const int t = threadIdx.x;

  if (bid < 2048) {
    // ---- transpose-cast w1: matrix z, tile = 64 k-rows x 64 n-cols ----
    const int z = bid >> 8;
    const int rem = bid & 255;
    const int k0 = (rem >> 4) * 64;
    const int n0 = (rem & 15) * 64;
    const float* src = w1 + (size_t)z * DIM * DIM;
    bf16_t* dst = w1t + (size_t)z * DIM * DIM;
    const int c4 = t & 15;
    const int rr = t >> 4;
    float4 v[4];
#pragma unroll
    for (int r = 0; r < 4; ++r)
      v[r] = *(const float4*)(src + (size_t)(k0 + rr * 4 + r) * DIM + n0 + c4 * 4);
    const float* vp = (const float*)v;
#pragma unroll
    for (int c = 0; c < 4; ++c) {
      bf16x4 o;
#pragma unroll
      for (int jk = 0; jk < 4; ++jk) o[jk] = (bf16_t)vp[jk * 4 + c];
      *(bf16x4*)(tileb + (c4 * 4 + c) * 144 + rr * 8) = o;
    }
    __syncthreads();
#pragma unroll
    for (int ii = 0; ii < 2; ++ii) {
      const int n = (t >> 3) + 32 * ii;
      const int j = t & 7;
      bf16x8 vv = *(const bf16x8*)(tileb + n * 144 + j * 16);
      *(bf16x8*)(dst + (size_t)(n0 + n) * DIM + k0 + j * 8) = vv;
    }
  } else if (bid < 2048 + 512) {
    // ---- cast x ----
    const int i0 = (bid - 2048) * 2048 + t;
    float4 v[8];
#pragma unroll
    for (int i = 0; i < 8; ++i) v[i] = ((const float4*)x)[i0 + i * 256];
#pragma unroll
    for (int i = 0; i < 8; ++i) {
      bf16x4 o;
      o[0] = (bf16_t)v[i].x; o[1] = (bf16_t)v[i].y;
      o[2] = (bf16_t)v[i].z; o[3] = (bf16_t)v[i].w;
      ((bf16x4*)xb)[i0 + i * 256] = o;
    }
  } else {
    // ---- router ----
    const int p = t >> 2, seg = t & 3;
    const int b = p >> 3, e = p & 7;
    const float4* dv = (const float4*)(dec + b * DIM + seg * 256);
    const float4* wv = (const float4*)(rw + e * DIM + seg * 256);
    float s = 0.f;
#pragma unroll 8
    for (int i = 0; i < 64; ++i) {
      float4 a = dv[i], c = wv[i];
      s += a.x * c.x + a.y * c.y + a.z * c.z + a.w * c.w;
    }
    part[t] = s;
    __syncthreads();
    if (seg == 0) {
      float l = part[t] + part[t + 1] + part[t + 2] + part[t + 3] + rb[e];
      lg64[p] = l;
      out_logits[p] = l;
    }
    __syncthreads();
    if (t < 8) {
      float l[8];
      float mx = -1e30f;
#pragma unroll
      for (int k = 0; k < 8; ++k) { l[k] = lg64[t * 8 + k]; mx = fmaxf(mx, l[k]); }
      float pe[8];
      float sum = 0.f;
#pragma unroll
      for (int k = 0; k < 8; ++k) { pe[k] = expf(l[k] - mx); sum += pe[k]; }
      float inv = 1.f / sum;
#pragma unroll
      for (int k = 0; k < 8; ++k) { pe[k] *= inv; probs[t * 8 + k] = pe[k]; }
      int i0 = 0;
#pragma unroll
      for (int k = 1; k < 8; ++k) if (pe[k] > pe[i0]) i0 = k;
      int i1 = (i0 == 0) ? 1 : 0;
#pragma unroll
      for (int k = 0; k < 8; ++k) if (k != i0 && pe[k] > pe[i1]) i1 = k;
      float p0 = pe[i0], p1 = pe[i1];
      float invs = 1.f / (p0 + p1);
      idx_ws[t * 2] = i0;
      idx_ws[t * 2 + 1] = i1;
      w_ws[t * 2] = p0 * invs;
      w_ws[t * 2 + 1] = p1 * invs;
#pragma unroll
      for (int k = 0; k < 8; ++k) {
        float m = (k == i0 || k == i1) ? 1.f : 0.f;
        msk[t * 8 + k] = m;
        out_mask[t * 8 + k] = m;
      }
    }
    __syncthreads();
    if (t == 0) {
      float aux = 0.f;
#pragma unroll
      for (int k = 0; k < 8; ++k) {
        float mp = 0.f, mm = 0.f;
#pragma unroll
        for (int bb = 0; bb < 8; ++bb) { mp += probs[bb * 8 + k]; mm += msk[bb * 8 + k]; }
        aux += (mp * 0.125f) * (mm * 0.125f);
      }
      out_aux[0] = 8.f * aux;
    }
  }
}

// ---------------------------------------------------------------------------
// GEMM1 (R9 consolidation): R3's best-measured kloop (256-thr, 128x128 tile,
// BK=32, 3-buffer depth-2, counted vmcnt(4); 48KB LDS -> 3 blocks/CU) +
// R7's hosted w2-transpose blocks + T1 XCD swizzle on the 512 gemm blocks
// (512 = 8 XCD x 64: consecutive in-XCD blocks share the 256KB A-panel ->
// L2 hits instead of L3 re-reads).
// grid 1-D: 512 gemm + 1024 transpose (2 tiles each), 256 thr.
// ---------------------------------------------------------------------------
__global__ __launch_bounds__(256, 2) void gemm1_kernel(const bf16_t* __restrict__ xb,
                                                       const bf16_t* __restrict__ w1t,
                                                       const float* __restrict__ b1,
                                                       const int* __restrict__ topk_idx,
                                                       bf16_t* __restrict__ hidden,
                                                       const float* __restrict__ w2,
                                                       bf16_t* __restrict__ w2t) {
  __shared__ __align__(16) char smem[49152];   // sA 3x8K | sB 3x8K; epilogue 34816
  const int bid = blockIdx.x;
  const int tid = threadIdx.x;

  if (bid >= 512) {
    // ---- hosted w2 transpose: 2 sequential 64k x 64n tiles (R8 body) ----
    char* tb = smem;
    const int base = (bid - 512) * 2;
#pragma unroll
    for (int it = 0; it < 2; ++it) {
      const int tile = base + it;                // 0..2047
      const int z = tile >> 8;                   // 8 matrices
      const int rem = tile & 255;
      const int k0 = (rem >> 4) * 64;
      const int n0 = (rem & 15) * 64;
      const float* src = w2 + (size_t)z * DIM * DIM;
      bf16_t* dst = w2t + (size_t)z * DIM * DIM;
      const int c4 = tid & 15;
      const int rr = tid >> 4;
      float4 v[4];
#pragma unroll
      for (int r = 0; r < 4; ++r)
        v[r] = *(const float4*)(src + (size_t)(k0 + rr * 4 + r) * DIM + n0 + c4 * 4);
      const float* vp = (const float*)v;
#pragma unroll
      for (int c = 0; c < 4; ++c) {
        bf16x4 o;
#pragma unroll
        for (int jk = 0; jk < 4; ++jk) o[jk] = (bf16_t)vp[jk * 4 + c];
        *(bf16x4*)(tb + (c4 * 4 + c) * 144 + rr * 8) = o;
      }
      __syncthreads();
#pragma unroll
      for (int ii = 0; ii < 2; ++ii) {
        const int n = (tid >> 3) + 32 * ii;
        const int j = tid & 7;
        bf16x8 vv = *(const bf16x8*)(tb + n * 144 + j * 16);
        *(bf16x8*)(dst + (size_t)(n0 + n) * DIM + k0 + j * 8) = vv;
      }
      __syncthreads();                           // before next tile's writes
    }
    return;
  }

  // ---- gemm: T1 XCD-chunked swizzle, then 1-D decode ----
  // default dispatch: bid%8 = XCD.  Map so each XCD gets a contiguous
  // 64-block chunk: wg = (bid&7)*64 + (bid>>3).  Within a chunk, bN varies
  // fastest -> 8 consecutive blocks share (bM,slot) = one A-panel.
  const int wg = (bid & 7) * 64 + (bid >> 3);
  const int bN = wg & 7, bM = (wg >> 3) & 3, slot = wg >> 5;
  const int t = tid;
  const int b = slot >> 1;
  const int e = topk_idx[slot];

  const bf16_t* A  = xb + ((size_t)b * SEQL + bM * 128) * DIM;
  const bf16_t* Bt = w1t + ((size_t)e * DIM + bN * 128) * DIM;

  char* sA = smem;            // 3 buffers x 8192
  char* sB = smem + 24576;    // 3 buffers x 8192

  // staging addresses (XOR-swizzled global source -> linear LDS dest)
  const int rl = t >> 2, cp = (t & 3) ^ (rl & 3);   // rows 0..63
  const bf16_t* ga0 = A + (size_t)rl * DIM + cp * 8;
  const bf16_t* ga1 = ga0 + (size_t)64 * DIM;
  const bf16_t* gb0 = Bt + (size_t)rl * DIM + cp * 8;
  const bf16_t* gb1 = gb0 + (size_t)64 * DIM;

  // fragment read pointers (R3-verified geometry)
  const int lane = t & 63, w = t >> 6;
  const int wr = w >> 1, wc = w & 1;
  const int m15 = lane & 15, q = lane >> 4;
  const char* ra[4];
  const char* rb[4];
#pragma unroll
  for (int i = 0; i < 4; ++i) {
    const int r = wr * 64 + i * 16 + m15;
    ra[i] = sA + r * 64 + ((q ^ (r & 3)) * 16);
    const int n = wc * 64 + i * 16 + m15;
    rb[i] = sB + n * 64 + ((q ^ (n & 3)) * 16);
  }

  f32x4 acc[4][4];
#pragma unroll
  for (int i = 0; i < 4; ++i)
#pragma unroll
    for (int j = 0; j < 4; ++j) acc[i][j] = {0.f, 0.f, 0.f, 0.f};

  // prologue: stage k-tiles 0 and 1 into buffers 0 and 1 (8 loads/thread)
  glds16(ga0, sA + t * 16);
  glds16(ga1, sA + 4096 + t * 16);
  glds16(gb0, sB + t * 16);
  glds16(gb1, sB + 4096 + t * 16);
  glds16(ga0 + 32, sA + 8192 + t * 16);
  glds16(ga1 + 32, sA + 8192 + 4096 + t * 16);
  glds16(gb0 + 32, sB + 8192 + t * 16);
  glds16(gb1 + 32, sB + 8192 + 4096 + t * 16);

  int cur = 0;                          // kt % 3
  for (int kt = 0; kt < 32; ++kt) {
    if (kt < 31) {
      asm volatile("s_waitcnt vmcnt(4)" ::: "memory");   // stage(kt) landed
    } else {
      asm volatile("s_waitcnt vmcnt(0)" ::: "memory");
    }
    __builtin_amdgcn_s_barrier();
    asm volatile("" ::: "memory");
    if (kt < 30) {                      // prefetch kt+2 into rotated buffer
      int nb = cur + 2; if (nb >= 3) nb -= 3;
      const int off = (kt + 2) * 32;
      char* dA = sA + nb * 8192 + t * 16;
      char* dB = sB + nb * 8192 + t * 16;
      glds16(ga0 + off, dA);
      glds16(ga1 + off, dA + 4096);
      glds16(gb0 + off, dB);
      glds16(gb1 + off, dB + 4096);
    }
    bf16x8 af[4], bfr[4];
#pragma unroll
    for (int i = 0; i < 4; ++i) af[i] = *(const bf16x8*)(ra[i] + cur * 8192);
#pragma unroll
    for (int j = 0; j < 4; ++j) bfr[j] = *(const bf16x8*)(rb[j] + cur * 8192);
    __builtin_amdgcn_s_setprio(1);
#pragma unroll
    for (int i = 0; i < 4; ++i)
#pragma unroll
      for (int j = 0; j < 4; ++j)
        acc[i][j] = __builtin_amdgcn_mfma_f32_16x16x32_bf16(af[i], bfr[j], acc[i][j], 0, 0, 0);
    __builtin_amdgcn_s_setprio(0);
    cur += 1; if (cur == 3) cur = 0;
  }

  // epilogue: bias + relu + cast, LDS bounce for 16B stores.
  // C/D layout: col = lane&15, row = quad*4 + reg (m89-verified).
  __syncthreads();
  bf16_t* hb = (bf16_t*)smem;            // [128][136] halfwords
  const float* be = b1 + e * DIM;
#pragma unroll
  for (int i = 0; i < 4; ++i)
#pragma unroll
    for (int j = 0; j < 4; ++j) {
      const int colL = wc * 64 + j * 16 + m15;
      const float bias = be[bN * 128 + colL];
#pragma unroll
      for (int r = 0; r < 4; ++r) {
        const int rowL = wr * 64 + i * 16 + q * 4 + r;
        hb[rowL * 136 + colL] = (bf16_t)fmaxf(acc[i][j][r] + bias, 0.f);
      }
    }
  __syncthreads();
  bf16_t* H = hidden + (size_t)slot * SEQL * DIM + ((size_t)bM * 128) * DIM + bN * 128;
#pragma unroll
  for (int ii = 0; ii < 8; ++ii) {
    const int r = (t >> 4) + 16 * ii;
    const int c = t & 15;
    bf16x8 vv = *(const bf16x8*)(hb + r * 136 + c * 8);
    *(bf16x8*)(H + (size_t)r * DIM + c * 8) = vv;
  }
}

// ---------------------------------------------------------------------------
// GEMM2 (R9): R4's verified paired-group 512-thr structure (3-buffer depth-2,
// counted vmcnt(4), 96KB LDS) + T1 XCD swizzle (256 = 8 XCD x 32 chunks).
// grid 1-D 256 blocks.
// ---------------------------------------------------------------------------
__global__ __launch_bounds__(512, 2) void gemm2_kernel(const bf16_t* __restrict__ hidden,
                                                       const bf16_t* __restrict__ w2t,
                                                       const float* __restrict__ b2,
                                                       const int* __restrict__ topk_idx,
                                                       const float* __restrict__ topk_w,
                                                       float* __restrict__ out) {
  __shared__ __align__(16) char smem[98304];   // per group: sA 3x8K | sB 3x8K
  const int tid = threadIdx.x;
  const int g = tid >> 8;
  const int t = tid & 255;
  // T1 swizzle + decode (bN fastest within a chunk -> A-panel sharing)
  const int raw = blockIdx.x;
  const int wg = (raw & 7) * 32 + (raw >> 3);
  const int bN = wg & 7, bM = (wg >> 3) & 3, b = wg >> 5;
  const int slot = b * 2 + g;
  const int e = topk_idx[slot];
  const float sg = topk_w[slot];

  const bf16_t* A  = hidden + ((size_t)slot * SEQL + bM * 128) * DIM;
  const bf16_t* Bt = w2t + ((size_t)e * DIM + bN * 128) * DIM;

  char* sA = smem + g * 49152;
  char* sB = sA + 24576;

  const int rl = t >> 2, cp = (t & 3) ^ (rl & 3);          // rows 0..63
  const bf16_t* gA0 = A + (size_t)rl * DIM + cp * 8;
  const bf16_t* gA1 = gA0 + (size_t)64 * DIM;
  const bf16_t* gB0 = Bt + (size_t)rl * DIM + cp * 8;
  const bf16_t* gB1 = gB0 + (size_t)64 * DIM;

  const int lane = tid & 63, wgv = (tid >> 6) & 3;
  const int wr = wgv >> 1, wc = wgv & 1;
  const int m15 = lane & 15, q = lane >> 4;
  const char* ra[4];
  const char* rb[4];
#pragma unroll
  for (int i = 0; i < 4; ++i) {
    const int r = wr * 64 + i * 16 + m15;
    ra[i] = sA + r * 64 + ((q ^ (r & 3)) * 16);
    const int n = wc * 64 + i * 16 + m15;
    rb[i] = sB + n * 64 + ((q ^ (n & 3)) * 16);
  }

  f32x4 acc[4][4];
#pragma unroll
  for (int i = 0; i < 4; ++i)
#pragma unroll
    for (int j = 0; j < 4; ++j) acc[i][j] = {0.f, 0.f, 0.f, 0.f};

  // prologue: k-tiles 0 and 1 (8 loads/thread in flight)
  glds16(gA0, sA + t * 16);
  glds16(gA1, sA + 4096 + t * 16);
  glds16(gB0, sB + t * 16);
  glds16(gB1, sB + 4096 + t * 16);
  glds16(gA0 + 32, sA + 8192 + t * 16);
  glds16(gA1 + 32, sA + 8192 + 4096 + t * 16);
  glds16(gB0 + 32, sB + 8192 + t * 16);
  glds16(gB1 + 32, sB + 8192 + 4096 + t * 16);

  int cur = 0;
  for (int kt = 0; kt < 32; ++kt) {
    if (kt < 31) {
      asm volatile("s_waitcnt vmcnt(4)" ::: "memory");
    } else {
      asm volatile("s_waitcnt vmcnt(0)" ::: "memory");
    }
    __builtin_amdgcn_s_barrier();
    asm volatile("" ::: "memory");
    if (kt < 30) {
      int nb = cur + 2; if (nb >= 3) nb -= 3;
      const int off = (kt + 2) * 32;
      char* dA = sA + nb * 8192 + t * 16;
      char* dB = sB + nb * 8192 + t * 16;
      glds16(gA0 + off, dA);
      glds16(gA1 + off, dA + 4096);
      glds16(gB0 + off, dB);
      glds16(gB1 + off, dB + 4096);
    }
    bf16x8 af[4], bfr[4];
#pragma unroll
    for (int i = 0; i < 4; ++i) af[i] = *(const bf16x8*)(ra[i] + cur * 8192);
#pragma unroll
    for (int j = 0; j < 4; ++j) bfr[j] = *(const bf16x8*)(rb[j] + cur * 8192);
    __builtin_amdgcn_s_setprio(1);
#pragma unroll
    for (int i = 0; i < 4; ++i)
#pragma unroll
      for (int j = 0; j < 4; ++j)
        acc[i][j] = __builtin_amdgcn_mfma_f32_16x16x32_bf16(af[i], bfr[j], acc[i][j], 0, 0, 0);
    __builtin_amdgcn_s_setprio(0);
    cur += 1; if (cur == 3) cur = 0;
  }

  // ---- combine: group1 -> LDS scratch (16KB chunks) -> group0 adds ----
  __syncthreads();               // all staging reads done; smem reusable
  float* scr = (float*)smem;     // [16][256] fp32 per chunk
  const float w0 = topk_w[b * 2], w1v = topk_w[b * 2 + 1];
  const float* be0 = b2 + topk_idx[b * 2] * DIM;
  const float* be1 = b2 + topk_idx[b * 2 + 1] * DIM;
  float* O = out + (size_t)b * SEQL * DIM;
#pragma unroll
  for (int i = 0; i < 4; ++i) {
    if (g == 1) {
#pragma unroll
      for (int j = 0; j < 4; ++j)
#pragma unroll
        for (int r = 0; r < 4; ++r)
          scr[(j * 4 + r) * 256 + t] = sg * acc[i][j][r];
    }
    __syncthreads();
    if (g == 0) {
#pragma unroll
      for (int j = 0; j < 4; ++j) {
        const int col = bN * 128 + wc * 64 + j * 16 + m15;
        const float bb = w0 * be0[col] + w1v * be1[col];
        const int row = bM * 128 + wr * 64 + i * 16 + q * 4;
#pragma unroll
        for (int r = 0; r < 4; ++r)
          O[(size_t)(row + r) * DIM + col] =
              sg * acc[i][j][r] + scr[(j * 4 + r) * 256 + t] + bb;
      }
    }
    __syncthreads();
  }
}

// ---------------------------------------------------------------------------
extern "C" void kernel_launch(void* const* d_in, const int* in_sizes, int n_in,
                              void* d_out, int out_size, void* d_ws, size_t ws_size,
                              hipStream_t stream) {
  const float* x   = (const float*)d_in[0];
  const float* dec = (const float*)d_in[1];
  const float* rw  = (const float*)d_in[2];
  const float* rb  = (const float*)d_in[3];
  const float* w1  = (const float*)d_in[4];
  const float* w2  = (const float*)d_in[5];
  const float* b1  = (const float*)d_in[6];
  const float* b2  = (const float*)d_in[7];
  float* out = (float*)d_out;

  // ws layout: xb 8MB | w1t 16MB | w2t 16MB | hidden 16MB | router scratch
  char* ws = (char*)d_ws;
  bf16_t* xb   = (bf16_t*)(ws);
  bf16_t* w1t  = (bf16_t*)(ws + (8u << 20));
  bf16_t* w2t  = (bf16_t*)(ws + (24u << 20));
  bf16_t* hid  = (bf16_t*)(ws + (40u << 20));
  int*    idxw = (int*)(ws + (56u << 20));
  float*  ww   = (float*)(ws + (56u << 20) + 64);

  hipLaunchKernelGGL(prep_kernel, dim3(2048 + 512 + 1), dim3(256), 0, stream,
                     x, dec, rw, rb, w1, w2, xb, w1t, w2t,
                     out + OFF_AUX, out + OFF_MASK, out + OFF_LOGITS, idxw, ww);
  hipLaunchKernelGGL(gemm1_kernel, dim3(512 + 1024), dim3(256), 0, stream,
                     xb, w1t, b1, idxw, hid, w2, w2t);
  hipLaunchKernelGGL(gemm2_kernel, dim3(256), dim3(512), 0, stream,
                     hid, w2t, b2, idxw, ww, out);
}